// Round 14
// baseline (358.981 us; speedup 1.0000x reference)
//
#include <hip/hip_runtime.h>
#include <hip/hip_bf16.h>

// Router MLP: X[16384,2048] @ W1[2048,1024] -> relu -> @ W2[1024,8] -> softmax -> top2
// R14: single-f16 MFMA GEMM + fp32 recompute of ambiguous rows.
// Recompute rebuilt: 1024-thread blocks, 32 cols/block (W1 register-stationary,
// 64 VGPR), full-wave shfl reduce, RGROUPS=16 -> X redundancy 128x -> 32x.
// Outputs (flat f32): logits[16384*8] | weights[16384*2] | indices-as-float[16384*2]

#define HDIM 2048
#define HM 1024
#define NROWS 16384
#define NE 8
#define KSTEPS 32       // 2048 / 64
#define TH_FLAG 0.0025f
#define RGROUPS 16

typedef _Float16 f16;
typedef f16 f16x8 __attribute__((ext_vector_type(8)));
typedef __fp16 h16x2 __attribute__((ext_vector_type(2)));
typedef float f32x4 __attribute__((ext_vector_type(4)));

union frag8 {
  f16x8 v;
  h16x2 p[4];
};

__device__ __forceinline__ void gload16(const void* g, void* l) {
  __builtin_amdgcn_global_load_lds(
      (const __attribute__((address_space(1))) void*)g,
      (__attribute__((address_space(3))) void*)l, 16, 0, 0);
}

// ---- prep: W1 [2048][1024] f32 -> hi-f16 swizzled BK=64 LDS-image tiles ----
__global__ __launch_bounds__(256) void prep_w1(const float* __restrict__ W1,
                                               f16* __restrict__ W1h) {
  const int nb = blockIdx.x & 3;
  const int kt = blockIdx.x >> 2;  // 0..31
  const int r = threadIdx.x;       // 0..255
  const int n = nb * 256 + r;
  const int k0 = kt * 64;
  f16 hi[64];
#pragma unroll
  for (int kk = 0; kk < 64; ++kk)
    hi[kk] = (f16)W1[(size_t)(k0 + kk) * HM + n];
  f16* dst = W1h + (size_t)(nb * 32 + kt) * 16384 + r * 64;
#pragma unroll
  for (int sp = 0; sp < 8; ++sp) {
    int s = sp ^ (r & 7);
    f16x8 v;
#pragma unroll
    for (int j = 0; j < 8; ++j) v[j] = hi[8 * s + j];
    *(f16x8*)(dst + sp * 8) = v;
  }
}

// ---- main GEMM: 256x256 tile, BK=64, 8 waves (2x4), f16 single product -----
__global__ __launch_bounds__(512, 2) void router_mfma(
    const float* __restrict__ X, const f16* __restrict__ W1h,
    const float* __restrict__ b1, const float* __restrict__ W2,
    float* __restrict__ pl) {
  const int bid = blockIdx.x;
  const int wg = (bid & 7) * 32 + (bid >> 3);  // XCD swizzle
  const int rb = wg >> 2;  // 0..63
  const int nb = wg & 3;   // 0..3

  const int t = threadIdx.x;
  const int lane = t & 63;
  const int wave = t >> 6;     // 0..7
  const int wm = wave >> 2;    // 0..1 (128 rows)
  const int wn = wave & 3;     // 0..3 (64 cols)
  const int lane15 = lane & 15;
  const int lgrp = lane >> 4;  // 0..3

  extern __shared__ char smem[];  // [2][65536]: A image 32KB | B image 32KB

  const int srow = t >> 1;
  const int shalf = t & 1;
  const float* Xr = X + (size_t)(rb * 256 + srow) * HDIM + shalf * 32;
  const int sm = srow & 7;
  int woff[4];
#pragma unroll
  for (int i = 0; i < 4; ++i)
    woff[i] = srow * 128 + (((shalf * 4 + i) ^ sm) << 4);

  const char* W1hB = (const char*)W1h + (size_t)nb * 32 * 32768;
  const int t16 = t * 16;

#define GLB(KT, BUF)                                                      \
  {                                                                       \
    char* bB_ = smem + (BUF) * 65536 + 32768;                             \
    _Pragma("unroll")                                                     \
    for (int i_ = 0; i_ < 4; ++i_)                                        \
      gload16(W1hB + (((size_t)(KT)) << 15) + i_ * 8192 + t16,            \
              bB_ + i_ * 8192 + t16);                                     \
  }

#define HIWR(BUF, X0, X1, X2, X3, X4, X5, X6, X7)                         \
  {                                                                       \
    char* bA_ = smem + (BUF) * 65536;                                     \
    frag8 v0_, v1_, v2_, v3_;                                             \
    v0_.p[0] = __builtin_amdgcn_cvt_pkrtz(X0.x, X0.y);                    \
    v0_.p[1] = __builtin_amdgcn_cvt_pkrtz(X0.z, X0.w);                    \
    v0_.p[2] = __builtin_amdgcn_cvt_pkrtz(X1.x, X1.y);                    \
    v0_.p[3] = __builtin_amdgcn_cvt_pkrtz(X1.z, X1.w);                    \
    v1_.p[0] = __builtin_amdgcn_cvt_pkrtz(X2.x, X2.y);                    \
    v1_.p[1] = __builtin_amdgcn_cvt_pkrtz(X2.z, X2.w);                    \
    v1_.p[2] = __builtin_amdgcn_cvt_pkrtz(X3.x, X3.y);                    \
    v1_.p[3] = __builtin_amdgcn_cvt_pkrtz(X3.z, X3.w);                    \
    v2_.p[0] = __builtin_amdgcn_cvt_pkrtz(X4.x, X4.y);                    \
    v2_.p[1] = __builtin_amdgcn_cvt_pkrtz(X4.z, X4.w);                    \
    v2_.p[2] = __builtin_amdgcn_cvt_pkrtz(X5.x, X5.y);                    \
    v2_.p[3] = __builtin_amdgcn_cvt_pkrtz(X5.z, X5.w);                    \
    v3_.p[0] = __builtin_amdgcn_cvt_pkrtz(X6.x, X6.y);                    \
    v3_.p[1] = __builtin_amdgcn_cvt_pkrtz(X6.z, X6.w);                    \
    v3_.p[2] = __builtin_amdgcn_cvt_pkrtz(X7.x, X7.y);                    \
    v3_.p[3] = __builtin_amdgcn_cvt_pkrtz(X7.z, X7.w);                    \
    *(f16x8*)(bA_ + woff[0]) = v0_.v;                                     \
    *(f16x8*)(bA_ + woff[1]) = v1_.v;                                     \
    *(f16x8*)(bA_ + woff[2]) = v2_.v;                                     \
    *(f16x8*)(bA_ + woff[3]) = v3_.v;                                     \
  }

  f32x4 acc[8][4];
#pragma unroll
  for (int i = 0; i < 8; ++i)
#pragma unroll
    for (int j = 0; j < 4; ++j) acc[i][j] = (f32x4){0.f, 0.f, 0.f, 0.f};

  // ---- prologue ----
  {
    GLB(0, 0);
    GLB(1, 1);
    float4 a[8], c[8];
#pragma unroll
    for (int i = 0; i < 8; ++i) a[i] = *(const float4*)(Xr + 4 * i);
#pragma unroll
    for (int i = 0; i < 8; ++i) c[i] = *(const float4*)(Xr + 64 + 4 * i);
    asm volatile("s_waitcnt vmcnt(0)" ::: "memory");
    HIWR(0, a[0], a[1], a[2], a[3], a[4], a[5], a[6], a[7]);
    HIWR(1, c[0], c[1], c[2], c[3], c[4], c[5], c[6], c[7]);
    asm volatile("s_waitcnt lgkmcnt(0)" ::: "memory");
  }
  __builtin_amdgcn_s_barrier();

  const int l7 = lane & 7;
  const int offK0 = ((lgrp ^ l7) << 4);
  const int offK1 = (((4 + lgrp) ^ l7) << 4);
  const int arow0 = (wm * 128 + lane15) * 128;
  const int bcol0 = (wn * 64 + lane15) * 128;

  int cur = 0;
#pragma unroll 1
  for (int kti = 0; kti < KSTEPS; ++kti) {
    const char* ldsA = smem + cur * 65536;
    const char* ldsB = ldsA + 32768;
    const bool stage2 = (kti + 2 < KSTEPS);

    float4 xr[8];
    if (stage2) {
      const float* xs = Xr + (kti + 2) * 64;
#pragma unroll
      for (int i = 0; i < 8; ++i) xr[i] = *(const float4*)(xs + 4 * i);
    }

    frag8 b[4][2];
#pragma unroll
    for (int ni = 0; ni < 4; ++ni) {
      const char* cp = ldsB + bcol0 + ni * 16 * 128;
      b[ni][0].v = *(const f16x8*)(cp + offK0);
      b[ni][1].v = *(const f16x8*)(cp + offK1);
    }

    frag8 a0, a1, na0, na1;
    {
      const char* rp = ldsA + arow0;
      a0.v = *(const f16x8*)(rp + offK0);
      a1.v = *(const f16x8*)(rp + offK1);
    }
#pragma unroll
    for (int mi = 0; mi < 8; ++mi) {
      if (mi < 7) {
        const char* rp = ldsA + arow0 + (mi + 1) * 16 * 128;
        na0.v = *(const f16x8*)(rp + offK0);
        na1.v = *(const f16x8*)(rp + offK1);
      }
      __builtin_amdgcn_s_setprio(1);
#pragma unroll
      for (int ni = 0; ni < 4; ++ni)
        acc[mi][ni] = __builtin_amdgcn_mfma_f32_16x16x32_f16(
            a0.v, b[ni][0].v, acc[mi][ni], 0, 0, 0);
#pragma unroll
      for (int ni = 0; ni < 4; ++ni)
        acc[mi][ni] = __builtin_amdgcn_mfma_f32_16x16x32_f16(
            a1.v, b[ni][1].v, acc[mi][ni], 0, 0, 0);
      __builtin_amdgcn_s_setprio(0);
      a0 = na0;
      a1 = na1;
    }

    if (kti == KSTEPS - 1) break;
    __builtin_amdgcn_sched_barrier(0);
    __builtin_amdgcn_s_barrier();  // #1
    if (stage2) {
      GLB(kti + 2, cur);
      asm volatile("s_waitcnt vmcnt(4)" ::: "memory");
      HIWR(cur, xr[0], xr[1], xr[2], xr[3], xr[4], xr[5], xr[6], xr[7]);
      asm volatile("s_waitcnt lgkmcnt(0)" ::: "memory");
    } else {
      asm volatile("s_waitcnt vmcnt(0)" ::: "memory");
    }
    __builtin_amdgcn_s_barrier();  // #2
    cur ^= 1;
  }

  // ---- fused epilogue ----
  __syncthreads();
  float* red = (float*)smem;

  float bvals[4];
  float w2r[4][NE];
#pragma unroll
  for (int ni = 0; ni < 4; ++ni) {
    int c = nb * 256 + wn * 64 + ni * 16 + lane15;
    bvals[ni] = b1[c];
    const float* src = W2 + (size_t)c * NE;
#pragma unroll
    for (int e = 0; e < NE; ++e) w2r[ni][e] = src[e];
  }

#pragma unroll
  for (int mi = 0; mi < 8; ++mi) {
    float plr[4][NE];
#pragma unroll
    for (int j = 0; j < 4; ++j)
#pragma unroll
      for (int e = 0; e < NE; ++e) plr[j][e] = 0.f;
#pragma unroll
    for (int ni = 0; ni < 4; ++ni) {
#pragma unroll
      for (int j = 0; j < 4; ++j) {
        float h = acc[mi][ni][j] + bvals[ni];
        h = fmaxf(h, 0.f);
#pragma unroll
        for (int e = 0; e < NE; ++e) plr[j][e] = fmaf(h, w2r[ni][e], plr[j][e]);
      }
    }
#pragma unroll
    for (int m = 1; m < 16; m <<= 1)
#pragma unroll
      for (int j = 0; j < 4; ++j)
#pragma unroll
        for (int e = 0; e < NE; ++e)
          plr[j][e] += __shfl_xor(plr[j][e], m, 64);
    if (lane15 == 0) {
#pragma unroll
      for (int j = 0; j < 4; ++j) {
        int rr = wm * 128 + mi * 16 + lgrp * 4 + j;
#pragma unroll
        for (int e = 0; e < NE; ++e)
          red[(size_t)wn * 2048 + rr * NE + e] = plr[j][e];
      }
    }
  }
  __syncthreads();
  for (int i = t; i < 256 * NE; i += 512) {
    int r = i >> 3, e = i & 7;
    int row = rb * 256 + r;
    float s = red[i] + red[2048 + i] + red[4096 + i] + red[6144 + i];
    pl[((size_t)nb * NROWS + row) * NE + e] = s;
  }
}

// ---- finalize: sum partials + b2, softmax, top-2, flag ambiguous rows ------
__global__ __launch_bounds__(256) void router_finalize(
    const float* __restrict__ pl, const float* __restrict__ b2,
    float* __restrict__ out, int* __restrict__ meta, int cap) {
  int row = blockIdx.x * 256 + threadIdx.x;
  if (row >= NROWS) return;
  float l[NE];
#pragma unroll
  for (int e = 0; e < NE; ++e) l[e] = b2[e];
  for (int nb = 0; nb < 4; ++nb) {
    const float* src = pl + ((size_t)nb * NROWS + row) * NE;
#pragma unroll
    for (int e = 0; e < NE; ++e) l[e] += src[e];
  }
#pragma unroll
  for (int e = 0; e < NE; ++e) out[(size_t)row * NE + e] = l[e];

  float v0 = -1e30f, v1 = -1e30f, v2 = -1e30f;
  int i0 = 0, i1 = 0;
#pragma unroll
  for (int e = 0; e < NE; ++e) {
    float le = l[e];
    if (le > v0) {
      v2 = v1; v1 = v0; i1 = i0; v0 = le; i0 = e;
    } else if (le > v1) {
      v2 = v1; v1 = le; i1 = e;
    } else if (le > v2) {
      v2 = le;
    }
  }
  float s = 0.f;
#pragma unroll
  for (int e = 0; e < NE; ++e) s += expf(l[e] - v0);
  float inv = 1.f / s;

  size_t wbase = (size_t)NROWS * NE + (size_t)row * 2;
  out[wbase] = inv;
  out[wbase + 1] = expf(v1 - v0) * inv;
  size_t ibase = (size_t)NROWS * NE + (size_t)NROWS * 2 + (size_t)row * 2;
  out[ibase] = (float)i0;
  out[ibase + 1] = (float)i1;

  if ((v0 - v1 < TH_FLAG) || (v1 - v2 < TH_FLAG)) {
    int p = atomicAdd(meta, 1);
    if (p < cap) meta[4 + p] = row;
  }
}

// ---- recompute (R14): 1024 threads, 32 cols/block, W1 in regs --------------
// grid: 32 col-chunks x RGROUPS row-groups. thread t: csub = t>>8 (8-col sub),
// ksub = t&255 (k-chunk [8*ksub, +8)). Wave = one csub x 512 k -> full-wave
// shfl reduce; 16-wave LDS combine -> 32 hpart floats/block.
__global__ __launch_bounds__(1024) void recompute(
    const float* __restrict__ X, const float* __restrict__ W1,
    const int* __restrict__ meta, float* __restrict__ hpart, int cap) {
  const int cc = blockIdx.x & 31;
  const int rg = blockIdx.x >> 5;  // 0..RGROUPS-1
  const int t = threadIdx.x;
  const int csub = t >> 8;         // 0..3
  const int ksub = t & 255;
  const int c0 = cc * 32 + csub * 8;
  const int k0 = ksub * 8;
  f32x4 w[8][2];
#pragma unroll
  for (int i = 0; i < 8; ++i) {
    w[i][0] = *(const f32x4*)&W1[(size_t)(k0 + i) * HM + c0];
    w[i][1] = *(const f32x4*)&W1[(size_t)(k0 + i) * HM + c0 + 4];
  }
  const int n = min(meta[0], cap);
  const int wave = t >> 6;  // 0..15
  const int lane = t & 63;
  __shared__ float red[16][8];

  f32x4 x0, x1;
  if (rg < n) {
    const float* xr = X + (size_t)meta[4 + rg] * HDIM + k0;
    x0 = *(const f32x4*)xr;
    x1 = *(const f32x4*)(xr + 4);
  }
#pragma unroll 1
  for (int p = rg; p < n; p += RGROUPS) {
    f32x4 nx0, nx1;
    if (p + RGROUPS < n) {
      const float* xr = X + (size_t)meta[4 + p + RGROUPS] * HDIM + k0;
      nx0 = *(const f32x4*)xr;
      nx1 = *(const f32x4*)(xr + 4);
    }
    f32x4 p0 = {0.f, 0.f, 0.f, 0.f}, p1 = {0.f, 0.f, 0.f, 0.f};
#pragma unroll
    for (int i = 0; i < 4; ++i) {
      p0 += x0[i] * w[i][0];
      p1 += x0[i] * w[i][1];
    }
#pragma unroll
    for (int i = 0; i < 4; ++i) {
      p0 += x1[i] * w[4 + i][0];
      p1 += x1[i] * w[4 + i][1];
    }
#pragma unroll
    for (int m = 1; m < 64; m <<= 1) {
#pragma unroll
      for (int c = 0; c < 4; ++c) {
        p0[c] += __shfl_xor(p0[c], m, 64);
        p1[c] += __shfl_xor(p1[c], m, 64);
      }
    }
    if (lane == 0) {
      *(f32x4*)&red[wave][0] = p0;
      *(f32x4*)&red[wave][4] = p1;
    }
    __syncthreads();
    // waves 4*cs..4*cs+3 hold partials for csub cs; threads 0..31 finish
    if (t < 32) {
      int cs = t >> 3, c = t & 7;
      hpart[(size_t)p * 1024 + cc * 32 + cs * 8 + c] =
          red[cs * 4 + 0][c] + red[cs * 4 + 1][c] + red[cs * 4 + 2][c] +
          red[cs * 4 + 3][c];
    }
    __syncthreads();
    x0 = nx0;
    x1 = nx1;
  }
}

// ---- fin2: relu+W2+softmax+top2 on exact h, overwrite flagged rows ---------
__global__ __launch_bounds__(256) void fin2(
    const float* __restrict__ b1, const float* __restrict__ W2,
    const float* __restrict__ b2, const int* __restrict__ meta,
    const float* __restrict__ hpart, float* __restrict__ out, int cap) {
  const int b = blockIdx.x;
  const int n = min(meta[0], cap);
  if (b >= n) return;
  const int row = meta[4 + b];
  const int t = threadIdx.x;
  float plr[NE];
#pragma unroll
  for (int e = 0; e < NE; ++e) plr[e] = 0.f;
#pragma unroll
  for (int q = 0; q < 4; ++q) {
    int c = t + q * 256;
    float h = hpart[(size_t)b * 1024 + c] + b1[c];
    h = fmaxf(h, 0.f);
#pragma unroll
    for (int e = 0; e < NE; ++e)
      plr[e] = fmaf(h, W2[(size_t)c * NE + e], plr[e]);
  }
#pragma unroll
  for (int m = 1; m < 64; m <<= 1)
#pragma unroll
    for (int e = 0; e < NE; ++e) plr[e] += __shfl_xor(plr[e], m, 64);
  __shared__ float red[4][NE];
  if ((t & 63) == 0) {
#pragma unroll
    for (int e = 0; e < NE; ++e) red[t >> 6][e] = plr[e];
  }
  __syncthreads();
  if (t == 0) {
    float l[NE];
#pragma unroll
    for (int e = 0; e < NE; ++e)
      l[e] = red[0][e] + red[1][e] + red[2][e] + red[3][e] + b2[e];
#pragma unroll
    for (int e = 0; e < NE; ++e) out[(size_t)row * NE + e] = l[e];
    float v0 = -1e30f, v1 = -1e30f;
    int i0 = 0, i1 = 0;
#pragma unroll
    for (int e = 0; e < NE; ++e) {
      float le = l[e];
      if (le > v0) {
        v1 = v0; i1 = i0; v0 = le; i0 = e;
      } else if (le > v1) {
        v1 = le; i1 = e;
      }
    }
    float s = 0.f;
#pragma unroll
    for (int e = 0; e < NE; ++e) s += expf(l[e] - v0);
    float inv = 1.f / s;
    size_t wbase = (size_t)NROWS * NE + (size_t)row * 2;
    out[wbase] = inv;
    out[wbase + 1] = expf(v1 - v0) * inv;
    size_t ibase = (size_t)NROWS * NE + (size_t)NROWS * 2 + (size_t)row * 2;
    out[ibase] = (float)i0;
    out[ibase + 1] = (float)i1;
  }
}

extern "C" void kernel_launch(void* const* d_in, const int* in_sizes, int n_in,
                              void* d_out, int out_size, void* d_ws,
                              size_t ws_size, hipStream_t stream) {
  const float* X = (const float*)d_in[0];
  const float* W1 = (const float*)d_in[1];
  const float* b1 = (const float*)d_in[2];
  const float* W2 = (const float*)d_in[3];
  const float* b2 = (const float*)d_in[4];
  float* out = (float*)d_out;

  // ws: pl 2MB @0 | W1h 4MB @2MB | meta 16KB @6MB | hpart [cap][1024] @6.5MB
  const size_t META_OFF = (size_t)6 * 1024 * 1024;
  const size_t HPART_OFF = META_OFF + 512 * 1024;
  float* pl = (float*)d_ws;
  f16* W1h = (f16*)((char*)d_ws + (size_t)2 * 1024 * 1024);
  int* meta = (int*)((char*)d_ws + META_OFF);
  float* hpart = (float*)((char*)d_ws + HPART_OFF);
  int cap = 0;
  if (ws_size > HPART_OFF + 4096)
    cap = (int)((ws_size - HPART_OFF) / 4096);
  if (cap > 768) cap = 768;

  (void)hipFuncSetAttribute((const void*)router_mfma,
                            hipFuncAttributeMaxDynamicSharedMemorySize, 131072);

  hipLaunchKernelGGL(prep_w1, dim3(128), dim3(256), 0, stream, W1, W1h);
  (void)hipMemsetAsync(meta, 0, 4, stream);
  hipLaunchKernelGGL(router_mfma, dim3(256), dim3(512), 131072, stream, X, W1h,
                     b1, W2, pl);
  hipLaunchKernelGGL(router_finalize, dim3(NROWS / 256), dim3(256), 0, stream,
                     pl, b2, out, meta, cap);
  hipLaunchKernelGGL(recompute, dim3(32 * RGROUPS), dim3(1024), 0, stream, X,
                     W1, meta, hpart, cap);
  hipLaunchKernelGGL(fin2, dim3(768), dim3(256), 0, stream, b1, W2, b2, meta,
                     hpart, out, cap);
}

// Round 15
// 206.592 us; speedup vs baseline: 1.7376x; 1.7376x over previous
//
#include <hip/hip_runtime.h>
#include <hip/hip_bf16.h>

// Router MLP: X[16384,2048] @ W1[2048,1024] -> relu -> @ W2[1024,8] -> softmax -> top2
// R15 = revert to R8 (best measured: 205.5 us total): f16 hi/lo split MFMA
// (Xh@Wh + Xh@Wl + Xl@Wh, fp32-class accuracy -> exact top-2 indices),
// 256x256x32 tile, 8 waves, 128KiB LDS dbuf, counted vmcnt, A reg-staged
// and split once per block, B pre-split+pre-swizzled via global_load_lds.
// Outputs (flat f32): logits[16384*8] | weights[16384*2] | indices-as-float[16384*2]

#define HDIM 2048
#define HM 1024
#define NROWS 16384
#define NE 8
#define KSTEPS 64  // 2048 / 32

typedef _Float16 f16;
typedef f16 f16x8 __attribute__((ext_vector_type(8)));
typedef __fp16 h16x2 __attribute__((ext_vector_type(2)));
typedef float f32x4 __attribute__((ext_vector_type(4)));

union frag8 {
  f16x8 v;
  h16x2 p[4];
};

__device__ __forceinline__ void gload16(const void* g, void* l) {
  __builtin_amdgcn_global_load_lds(
      (const __attribute__((address_space(1))) void*)g,
      (__attribute__((address_space(3))) void*)l, 16, 0, 0);
}

// ---- prep: W1 [2048][1024] f32 -> W1s swizzled LDS-image tiles -------------
// W1s[nb][ktidx] = 32KB image: 256 rows (n = nb*256+r) x 8 slots of 16B.
// LDS slot sp holds data slot s = sp^(r&7); s<4: hi f16 of W1[kt+8s..+8][n],
// s>=4: lo f16 (x - (f16)x).
__global__ __launch_bounds__(256) void prep_w1(const float* __restrict__ W1,
                                               f16* __restrict__ W1s) {
  const int nb = blockIdx.x & 3;
  const int ktidx = blockIdx.x >> 2;
  const int r = threadIdx.x;  // 0..255
  const int n = nb * 256 + r;
  const int kt = ktidx * 32;
  f16 hi[32], lo[32];
#pragma unroll
  for (int kk = 0; kk < 32; ++kk) {
    float x = W1[(size_t)(kt + kk) * HM + n];
    f16 h = (f16)x;
    hi[kk] = h;
    lo[kk] = (f16)(x - (float)h);
  }
  f16* dst = W1s + (size_t)(nb * 64 + ktidx) * 16384 + r * 64;
#pragma unroll
  for (int sp = 0; sp < 8; ++sp) {
    int s = sp ^ (r & 7);
    f16x8 v;
#pragma unroll
    for (int j = 0; j < 8; ++j)
      v[j] = (s < 4) ? hi[8 * s + j] : lo[8 * (s - 4) + j];
    *(f16x8*)(dst + sp * 8) = v;
  }
}

// ---- main GEMM: 256x256 tile, BK=32, 8 waves (2x4) -------------------------
__global__ __launch_bounds__(512, 2) void router_mfma(
    const float* __restrict__ X, const f16* __restrict__ W1s,
    const float* __restrict__ b1, const float* __restrict__ W2,
    float* __restrict__ pl) {
  // XCD swizzle: 256 wgs -> 32 contiguous per XCD; same-rb blocks cluster.
  const int bid = blockIdx.x;
  const int wg = (bid & 7) * 32 + (bid >> 3);
  const int rb = wg >> 2;  // 0..63
  const int nb = wg & 3;   // 0..3

  const int t = threadIdx.x;
  const int lane = t & 63;
  const int wave = t >> 6;       // 0..7
  const int wm = wave >> 2;      // 0..1  (128 rows each)
  const int wn = wave & 3;       // 0..3  (64 cols each)
  const int lane15 = lane & 15;
  const int lgrp = lane >> 4;    // 0..3

  extern __shared__ char smem[];  // [2][65536]: A image 32KB | B image 32KB

  // ---- A reg-staging: thread t owns row t>>1 (0..255), k-half t&1 ----
  const int srow = t >> 1;
  const int shalf = t & 1;
  const float* Xr = X + (size_t)(rb * 256 + srow) * HDIM + shalf * 16;
  const int sm = srow & 7;
  const int woff_h0 = srow * 128 + (((2 * shalf) ^ sm) << 4);
  const int woff_h1 = srow * 128 + (((2 * shalf + 1) ^ sm) << 4);
  const int woff_l0 = srow * 128 + (((4 + 2 * shalf) ^ sm) << 4);
  const int woff_l1 = srow * 128 + (((5 + 2 * shalf) ^ sm) << 4);

  const char* W1sB = (const char*)W1s + (size_t)nb * 64 * 32768;
  const int t16 = t * 16;

// issue the 4 B-staging gloads for tile KT into buffer BUF
#define GLB(KT, BUF)                                                      \
  {                                                                       \
    char* bB_ = smem + (BUF) * 65536 + 32768;                             \
    _Pragma("unroll")                                                     \
    for (int i_ = 0; i_ < 4; ++i_)                                        \
      gload16(W1sB + (((size_t)(KT)) << 15) + i_ * 8192 + t16,            \
              bB_ + i_ * 8192 + t16);                                     \
  }

// split 16 regs (x0..x3 float4) and ds_write the A image rows into BUF
#define SPLITWR(BUF, x0, x1, x2, x3)                                      \
  {                                                                       \
    char* bA_ = smem + (BUF) * 65536;                                     \
    frag8 hi0_, hi1_, lo0_, lo1_;                                         \
    hi0_.p[0] = __builtin_amdgcn_cvt_pkrtz(x0.x, x0.y);                   \
    hi0_.p[1] = __builtin_amdgcn_cvt_pkrtz(x0.z, x0.w);                   \
    hi0_.p[2] = __builtin_amdgcn_cvt_pkrtz(x1.x, x1.y);                   \
    hi0_.p[3] = __builtin_amdgcn_cvt_pkrtz(x1.z, x1.w);                   \
    hi1_.p[0] = __builtin_amdgcn_cvt_pkrtz(x2.x, x2.y);                   \
    hi1_.p[1] = __builtin_amdgcn_cvt_pkrtz(x2.z, x2.w);                   \
    hi1_.p[2] = __builtin_amdgcn_cvt_pkrtz(x3.x, x3.y);                   \
    hi1_.p[3] = __builtin_amdgcn_cvt_pkrtz(x3.z, x3.w);                   \
    lo0_.p[0] = __builtin_amdgcn_cvt_pkrtz(x0.x - (float)hi0_.p[0][0],    \
                                           x0.y - (float)hi0_.p[0][1]);   \
    lo0_.p[1] = __builtin_amdgcn_cvt_pkrtz(x0.z - (float)hi0_.p[1][0],    \
                                           x0.w - (float)hi0_.p[1][1]);   \
    lo0_.p[2] = __builtin_amdgcn_cvt_pkrtz(x1.x - (float)hi0_.p[2][0],    \
                                           x1.y - (float)hi0_.p[2][1]);   \
    lo0_.p[3] = __builtin_amdgcn_cvt_pkrtz(x1.z - (float)hi0_.p[3][0],    \
                                           x1.w - (float)hi0_.p[3][1]);   \
    lo1_.p[0] = __builtin_amdgcn_cvt_pkrtz(x2.x - (float)hi1_.p[0][0],    \
                                           x2.y - (float)hi1_.p[0][1]);   \
    lo1_.p[1] = __builtin_amdgcn_cvt_pkrtz(x2.z - (float)hi1_.p[1][0],    \
                                           x2.w - (float)hi1_.p[1][1]);   \
    lo1_.p[2] = __builtin_amdgcn_cvt_pkrtz(x3.x - (float)hi1_.p[2][0],    \
                                           x3.y - (float)hi1_.p[2][1]);   \
    lo1_.p[3] = __builtin_amdgcn_cvt_pkrtz(x3.z - (float)hi1_.p[3][0],    \
                                           x3.w - (float)hi1_.p[3][1]);   \
    *(f16x8*)(bA_ + woff_h0) = hi0_.v;                                    \
    *(f16x8*)(bA_ + woff_h1) = hi1_.v;                                    \
    *(f16x8*)(bA_ + woff_l0) = lo0_.v;                                    \
    *(f16x8*)(bA_ + woff_l1) = lo1_.v;                                    \
  }

  f32x4 acc[8][4];
#pragma unroll
  for (int i = 0; i < 8; ++i)
#pragma unroll
    for (int j = 0; j < 4; ++j) acc[i][j] = (f32x4){0.f, 0.f, 0.f, 0.f};

  // ---- prologue: stage tiles 0 (buf0) and 1 (buf1) ----
  {
    GLB(0, 0);
    GLB(1, 1);
    float4 a0 = *(const float4*)(Xr + 0);
    float4 a1 = *(const float4*)(Xr + 4);
    float4 a2 = *(const float4*)(Xr + 8);
    float4 a3 = *(const float4*)(Xr + 12);
    float4 c0 = *(const float4*)(Xr + 32);
    float4 c1 = *(const float4*)(Xr + 36);
    float4 c2 = *(const float4*)(Xr + 40);
    float4 c3 = *(const float4*)(Xr + 44);
    asm volatile("s_waitcnt vmcnt(0)" ::: "memory");
    SPLITWR(0, a0, a1, a2, a3);
    SPLITWR(1, c0, c1, c2, c3);
    asm volatile("s_waitcnt lgkmcnt(0)" ::: "memory");
  }
  __builtin_amdgcn_s_barrier();

  // A frag read constants (mi-independent swizzle since mi*16 % 8 == 0)
  const int arow_base = wm * 128 + lane15;
  const int offAh = ((lgrp ^ (lane15 & 7)) << 4);
  const int offAl = (((4 + lgrp) ^ (lane15 & 7)) << 4);

  int cur = 0;
#pragma unroll 1
  for (int kti = 0; kti < KSTEPS; ++kti) {
    const char* ldsA = smem + cur * 65536;
    const f16* ldsB = (const f16*)(ldsA + 32768);
    const bool stage2 = (kti + 2 < KSTEPS);

    // issue X reg-loads for tile kti+2 (latency hidden under this tile's MFMA)
    float4 x0, x1, x2, x3;
    if (stage2) {
      const float* xs = Xr + (kti + 2) * 32;
      x0 = *(const float4*)(xs + 0);
      x1 = *(const float4*)(xs + 4);
      x2 = *(const float4*)(xs + 8);
      x3 = *(const float4*)(xs + 12);
    }

    // B fragments (pre-split hi/lo, swizzled)
    frag8 bh[4], bl[4];
#pragma unroll
    for (int ni = 0; ni < 4; ++ni) {
      int c = wn * 64 + ni * 16 + lane15;
      bh[ni].v = *(const f16x8*)&ldsB[c * 64 + ((lgrp ^ (c & 7)) << 3)];
      bl[ni].v = *(const f16x8*)&ldsB[c * 64 + (((4 + lgrp) ^ (c & 7)) << 3)];
    }

    // rolling one-ahead A frag reads (pure f16 b128, no split)
    frag8 ah, al, nah, nal;
    {
      const char* rowp = ldsA + arow_base * 128;
      ah.v = *(const f16x8*)(rowp + offAh);
      al.v = *(const f16x8*)(rowp + offAl);
    }
#pragma unroll
    for (int mi = 0; mi < 8; ++mi) {
      if (mi < 7) {
        const char* rowp = ldsA + (arow_base + (mi + 1) * 16) * 128;
        nah.v = *(const f16x8*)(rowp + offAh);
        nal.v = *(const f16x8*)(rowp + offAl);
      }
      __builtin_amdgcn_s_setprio(1);
#pragma unroll
      for (int ni = 0; ni < 4; ++ni) {
        acc[mi][ni] = __builtin_amdgcn_mfma_f32_16x16x32_f16(
            ah.v, bh[ni].v, acc[mi][ni], 0, 0, 0);
        acc[mi][ni] = __builtin_amdgcn_mfma_f32_16x16x32_f16(
            ah.v, bl[ni].v, acc[mi][ni], 0, 0, 0);
        acc[mi][ni] = __builtin_amdgcn_mfma_f32_16x16x32_f16(
            al.v, bh[ni].v, acc[mi][ni], 0, 0, 0);
      }
      __builtin_amdgcn_s_setprio(0);
      ah = nah;
      al = nal;
    }

    if (kti == KSTEPS - 1) break;
    __builtin_amdgcn_sched_barrier(0);
    __builtin_amdgcn_s_barrier();  // #1: all waves done reading smem[cur]
    if (stage2) {
      GLB(kti + 2, cur);  // B(kti+2) in flight across the barrier
      // drain B(kti+1) + X regs (oldest), keep B(kti+2) (4 newest) in flight
      asm volatile("s_waitcnt vmcnt(4)" ::: "memory");
      SPLITWR(cur, x0, x1, x2, x3);
      asm volatile("s_waitcnt lgkmcnt(0)" ::: "memory");
    } else {
      asm volatile("s_waitcnt vmcnt(0)" ::: "memory");  // tail drain
    }
    __builtin_amdgcn_s_barrier();  // #2: smem[cur^1] (tile kti+1) ready
    cur ^= 1;
  }

  // ---- fused epilogue: relu(acc+b1) @ W2 chunk, 16-lane reduce ----
  __syncthreads();
  float* red = (float*)smem;  // [4][256][8] f32 = 32KB

  float bvals[4];
  float w2r[4][NE];
#pragma unroll
  for (int ni = 0; ni < 4; ++ni) {
    int c = nb * 256 + wn * 64 + ni * 16 + lane15;
    bvals[ni] = b1[c];
    const float* src = W2 + (size_t)c * NE;
#pragma unroll
    for (int e = 0; e < NE; ++e) w2r[ni][e] = src[e];
  }

#pragma unroll
  for (int mi = 0; mi < 8; ++mi) {
    float plr[4][NE];
#pragma unroll
    for (int j = 0; j < 4; ++j)
#pragma unroll
      for (int e = 0; e < NE; ++e) plr[j][e] = 0.f;
#pragma unroll
    for (int ni = 0; ni < 4; ++ni) {
#pragma unroll
      for (int j = 0; j < 4; ++j) {
        float h = acc[mi][ni][j] + bvals[ni];
        h = fmaxf(h, 0.f);
#pragma unroll
        for (int e = 0; e < NE; ++e) plr[j][e] = fmaf(h, w2r[ni][e], plr[j][e]);
      }
    }
#pragma unroll
    for (int m = 1; m < 16; m <<= 1)
#pragma unroll
      for (int j = 0; j < 4; ++j)
#pragma unroll
        for (int e = 0; e < NE; ++e)
          plr[j][e] += __shfl_xor(plr[j][e], m, 64);
    if (lane15 == 0) {
#pragma unroll
      for (int j = 0; j < 4; ++j) {
        int rr = wm * 128 + mi * 16 + lgrp * 4 + j;
#pragma unroll
        for (int e = 0; e < NE; ++e)
          red[(size_t)wn * 2048 + rr * NE + e] = plr[j][e];
      }
    }
  }
  __syncthreads();
  for (int i = t; i < 256 * NE; i += 512) {
    int r = i >> 3, e = i & 7;
    int row = rb * 256 + r;
    float s = red[i] + red[2048 + i] + red[4096 + i] + red[6144 + i];
    pl[((size_t)nb * NROWS + row) * NE + e] = s;
  }
}

// ---- finalize: sum partials + b2, softmax, top-2 ----------------------------
__global__ __launch_bounds__(256) void router_finalize(
    const float* __restrict__ pl, const float* __restrict__ b2,
    float* __restrict__ out) {
  int row = blockIdx.x * 256 + threadIdx.x;
  if (row >= NROWS) return;
  float l[NE];
#pragma unroll
  for (int e = 0; e < NE; ++e) l[e] = b2[e];
  for (int nb = 0; nb < 4; ++nb) {
    const float* src = pl + ((size_t)nb * NROWS + row) * NE;
#pragma unroll
    for (int e = 0; e < NE; ++e) l[e] += src[e];
  }
#pragma unroll
  for (int e = 0; e < NE; ++e) out[(size_t)row * NE + e] = l[e];

  float m = l[0];
#pragma unroll
  for (int e = 1; e < NE; ++e) m = fmaxf(m, l[e]);
  float p[NE], s = 0.f;
#pragma unroll
  for (int e = 0; e < NE; ++e) {
    p[e] = expf(l[e] - m);
    s += p[e];
  }
  float inv = 1.f / s;

  float v0 = -1.f, v1 = -1.f;
  int i0 = 0, i1 = 0;
#pragma unroll
  for (int e = 0; e < NE; ++e) {
    float pe = p[e];
    if (pe > v0) {
      v1 = v0; i1 = i0;
      v0 = pe; i0 = e;
    } else if (pe > v1) {
      v1 = pe; i1 = e;
    }
  }
  size_t wbase = (size_t)NROWS * NE + (size_t)row * 2;
  out[wbase] = v0 * inv;
  out[wbase + 1] = v1 * inv;
  size_t ibase = (size_t)NROWS * NE + (size_t)NROWS * 2 + (size_t)row * 2;
  out[ibase] = (float)i0;
  out[ibase + 1] = (float)i1;
}

extern "C" void kernel_launch(void* const* d_in, const int* in_sizes, int n_in,
                              void* d_out, int out_size, void* d_ws,
                              size_t ws_size, hipStream_t stream) {
  const float* X = (const float*)d_in[0];
  const float* W1 = (const float*)d_in[1];
  const float* b1 = (const float*)d_in[2];
  const float* W2 = (const float*)d_in[3];
  const float* b2 = (const float*)d_in[4];
  float* out = (float*)d_out;

  // ws: pl 2MB (at 0) | W1s 8MB (at +4MB)
  float* pl = (float*)d_ws;
  f16* W1s = (f16*)((char*)d_ws + (size_t)4 * 1024 * 1024);

  // allow 128 KiB dynamic LDS (non-stream runtime call; capture-safe)
  (void)hipFuncSetAttribute((const void*)router_mfma,
                            hipFuncAttributeMaxDynamicSharedMemorySize, 131072);

  hipLaunchKernelGGL(prep_w1, dim3(256), dim3(256), 0, stream, W1, W1s);
  hipLaunchKernelGGL(router_mfma, dim3(256), dim3(512), 131072, stream, X, W1s,
                     b1, W2, pl);
  hipLaunchKernelGGL(router_finalize, dim3(NROWS / 256), dim3(256), 0, stream,
                     pl, b2, out);
}

// Round 16
// 203.487 us; speedup vs baseline: 1.7641x; 1.0153x over previous
//
#include <hip/hip_runtime.h>
#include <hip/hip_bf16.h>

// Router MLP: X[16384,2048] @ W1[2048,1024] -> relu -> @ W2[1024,8] -> softmax -> top2
// R16 = R8 base + frag pre-read: tile kti+1's B fragments + A pair0 are read
// during kti's staging window (after vmcnt(4)+bar_mid, overlapping SPLITWR),
// so the mi-loop starts with operands in registers instead of a 10-read
// LDS burst that stalls all waves in lockstep.
// f16 hi/lo split MFMA (Xh@Wh + Xh@Wl + Xl@Wh), 256x256x32, 8 waves,
// 128KiB LDS dbuf, counted vmcnt(4), XOR-swizzled images.
// Outputs (flat f32): logits[16384*8] | weights[16384*2] | indices-as-float[16384*2]

#define HDIM 2048
#define HM 1024
#define NROWS 16384
#define NE 8
#define KSTEPS 64  // 2048 / 32

typedef _Float16 f16;
typedef f16 f16x8 __attribute__((ext_vector_type(8)));
typedef __fp16 h16x2 __attribute__((ext_vector_type(2)));
typedef float f32x4 __attribute__((ext_vector_type(4)));

union frag8 {
  f16x8 v;
  h16x2 p[4];
};

__device__ __forceinline__ void gload16(const void* g, void* l) {
  __builtin_amdgcn_global_load_lds(
      (const __attribute__((address_space(1))) void*)g,
      (__attribute__((address_space(3))) void*)l, 16, 0, 0);
}

// ---- prep: W1 [2048][1024] f32 -> W1s swizzled LDS-image tiles -------------
// W1s[nb][ktidx] = 32KB image: 256 rows (n = nb*256+r) x 8 slots of 16B.
// LDS slot sp holds data slot s = sp^(r&7); s<4: hi f16 of W1[kt+8s..+8][n],
// s>=4: lo f16 (x - (f16)x).
__global__ __launch_bounds__(256) void prep_w1(const float* __restrict__ W1,
                                               f16* __restrict__ W1s) {
  const int nb = blockIdx.x & 3;
  const int ktidx = blockIdx.x >> 2;
  const int r = threadIdx.x;  // 0..255
  const int n = nb * 256 + r;
  const int kt = ktidx * 32;
  f16 hi[32], lo[32];
#pragma unroll
  for (int kk = 0; kk < 32; ++kk) {
    float x = W1[(size_t)(kt + kk) * HM + n];
    f16 h = (f16)x;
    hi[kk] = h;
    lo[kk] = (f16)(x - (float)h);
  }
  f16* dst = W1s + (size_t)(nb * 64 + ktidx) * 16384 + r * 64;
#pragma unroll
  for (int sp = 0; sp < 8; ++sp) {
    int s = sp ^ (r & 7);
    f16x8 v;
#pragma unroll
    for (int j = 0; j < 8; ++j)
      v[j] = (s < 4) ? hi[8 * s + j] : lo[8 * (s - 4) + j];
    *(f16x8*)(dst + sp * 8) = v;
  }
}

// ---- main GEMM: 256x256 tile, BK=32, 8 waves (2x4) -------------------------
__global__ __launch_bounds__(512, 2) void router_mfma(
    const float* __restrict__ X, const f16* __restrict__ W1s,
    const float* __restrict__ b1, const float* __restrict__ W2,
    float* __restrict__ pl) {
  // XCD swizzle: 256 wgs -> 32 contiguous per XCD; same-rb blocks cluster.
  const int bid = blockIdx.x;
  const int wg = (bid & 7) * 32 + (bid >> 3);
  const int rb = wg >> 2;  // 0..63
  const int nb = wg & 3;   // 0..3

  const int t = threadIdx.x;
  const int lane = t & 63;
  const int wave = t >> 6;       // 0..7
  const int wm = wave >> 2;      // 0..1  (128 rows each)
  const int wn = wave & 3;       // 0..3  (64 cols each)
  const int lane15 = lane & 15;
  const int lgrp = lane >> 4;    // 0..3

  extern __shared__ char smem[];  // [2][65536]: A image 32KB | B image 32KB

  // ---- A reg-staging: thread t owns row t>>1 (0..255), k-half t&1 ----
  const int srow = t >> 1;
  const int shalf = t & 1;
  const float* Xr = X + (size_t)(rb * 256 + srow) * HDIM + shalf * 16;
  const int sm = srow & 7;
  const int woff_h0 = srow * 128 + (((2 * shalf) ^ sm) << 4);
  const int woff_h1 = srow * 128 + (((2 * shalf + 1) ^ sm) << 4);
  const int woff_l0 = srow * 128 + (((4 + 2 * shalf) ^ sm) << 4);
  const int woff_l1 = srow * 128 + (((5 + 2 * shalf) ^ sm) << 4);

  const char* W1sB = (const char*)W1s + (size_t)nb * 64 * 32768;
  const int t16 = t * 16;

// issue the 4 B-staging gloads for tile KT into buffer BUF
#define GLB(KT, BUF)                                                      \
  {                                                                       \
    char* bB_ = smem + (BUF) * 65536 + 32768;                             \
    _Pragma("unroll")                                                     \
    for (int i_ = 0; i_ < 4; ++i_)                                        \
      gload16(W1sB + (((size_t)(KT)) << 15) + i_ * 8192 + t16,            \
              bB_ + i_ * 8192 + t16);                                     \
  }

// split 16 regs (x0..x3 float4) and ds_write the A image rows into BUF
#define SPLITWR(BUF, x0, x1, x2, x3)                                      \
  {                                                                       \
    char* bA_ = smem + (BUF) * 65536;                                     \
    frag8 hi0_, hi1_, lo0_, lo1_;                                         \
    hi0_.p[0] = __builtin_amdgcn_cvt_pkrtz(x0.x, x0.y);                   \
    hi0_.p[1] = __builtin_amdgcn_cvt_pkrtz(x0.z, x0.w);                   \
    hi0_.p[2] = __builtin_amdgcn_cvt_pkrtz(x1.x, x1.y);                   \
    hi0_.p[3] = __builtin_amdgcn_cvt_pkrtz(x1.z, x1.w);                   \
    hi1_.p[0] = __builtin_amdgcn_cvt_pkrtz(x2.x, x2.y);                   \
    hi1_.p[1] = __builtin_amdgcn_cvt_pkrtz(x2.z, x2.w);                   \
    hi1_.p[2] = __builtin_amdgcn_cvt_pkrtz(x3.x, x3.y);                   \
    hi1_.p[3] = __builtin_amdgcn_cvt_pkrtz(x3.z, x3.w);                   \
    lo0_.p[0] = __builtin_amdgcn_cvt_pkrtz(x0.x - (float)hi0_.p[0][0],    \
                                           x0.y - (float)hi0_.p[0][1]);   \
    lo0_.p[1] = __builtin_amdgcn_cvt_pkrtz(x0.z - (float)hi0_.p[1][0],    \
                                           x0.w - (float)hi0_.p[1][1]);   \
    lo0_.p[2] = __builtin_amdgcn_cvt_pkrtz(x1.x - (float)hi0_.p[2][0],    \
                                           x1.y - (float)hi0_.p[2][1]);   \
    lo0_.p[3] = __builtin_amdgcn_cvt_pkrtz(x1.z - (float)hi0_.p[3][0],    \
                                           x1.w - (float)hi0_.p[3][1]);   \
    lo1_.p[0] = __builtin_amdgcn_cvt_pkrtz(x2.x - (float)hi1_.p[0][0],    \
                                           x2.y - (float)hi1_.p[0][1]);   \
    lo1_.p[1] = __builtin_amdgcn_cvt_pkrtz(x2.z - (float)hi1_.p[1][0],    \
                                           x2.w - (float)hi1_.p[1][1]);   \
    lo1_.p[2] = __builtin_amdgcn_cvt_pkrtz(x3.x - (float)hi1_.p[2][0],    \
                                           x3.y - (float)hi1_.p[2][1]);   \
    lo1_.p[3] = __builtin_amdgcn_cvt_pkrtz(x3.z - (float)hi1_.p[3][0],    \
                                           x3.w - (float)hi1_.p[3][1]);   \
    *(f16x8*)(bA_ + woff_h0) = hi0_.v;                                    \
    *(f16x8*)(bA_ + woff_h1) = hi1_.v;                                    \
    *(f16x8*)(bA_ + woff_l0) = lo0_.v;                                    \
    *(f16x8*)(bA_ + woff_l1) = lo1_.v;                                    \
  }

  // A frag read constants (mi-independent swizzle since mi*16 % 8 == 0)
  const int arow_base = wm * 128 + lane15;
  const int offAh = ((lgrp ^ (lane15 & 7)) << 4);
  const int offAl = (((4 + lgrp) ^ (lane15 & 7)) << 4);

// pre-read tile frags (all B + A pair0) from buffer BUF into bh/bl/a0h/a0l
#define PREREAD(BUF)                                                      \
  {                                                                       \
    const char* ldsA_ = smem + (BUF) * 65536;                             \
    const f16* ldsB_ = (const f16*)(ldsA_ + 32768);                       \
    _Pragma("unroll")                                                     \
    for (int ni_ = 0; ni_ < 4; ++ni_) {                                   \
      int c_ = wn * 64 + ni_ * 16 + lane15;                               \
      bh[ni_].v = *(const f16x8*)&ldsB_[c_ * 64 + ((lgrp ^ (c_ & 7)) << 3)]; \
      bl[ni_].v =                                                         \
          *(const f16x8*)&ldsB_[c_ * 64 + (((4 + lgrp) ^ (c_ & 7)) << 3)]; \
    }                                                                     \
    const char* rowp_ = ldsA_ + arow_base * 128;                          \
    a0h.v = *(const f16x8*)(rowp_ + offAh);                               \
    a0l.v = *(const f16x8*)(rowp_ + offAl);                               \
  }

  f32x4 acc[8][4];
#pragma unroll
  for (int i = 0; i < 8; ++i)
#pragma unroll
    for (int j = 0; j < 4; ++j) acc[i][j] = (f32x4){0.f, 0.f, 0.f, 0.f};

  // persistent pre-read fragments (tile kti's, loaded at kti-1's window)
  frag8 bh[4], bl[4], a0h, a0l;

  // ---- prologue: stage tiles 0 (buf0) and 1 (buf1); pre-read tile 0 ----
  {
    GLB(0, 0);
    GLB(1, 1);
    float4 a0 = *(const float4*)(Xr + 0);
    float4 a1 = *(const float4*)(Xr + 4);
    float4 a2 = *(const float4*)(Xr + 8);
    float4 a3 = *(const float4*)(Xr + 12);
    float4 c0 = *(const float4*)(Xr + 32);
    float4 c1 = *(const float4*)(Xr + 36);
    float4 c2 = *(const float4*)(Xr + 40);
    float4 c3 = *(const float4*)(Xr + 44);
    asm volatile("s_waitcnt vmcnt(0)" ::: "memory");
    SPLITWR(0, a0, a1, a2, a3);
    SPLITWR(1, c0, c1, c2, c3);
    asm volatile("s_waitcnt lgkmcnt(0)" ::: "memory");
  }
  __builtin_amdgcn_s_barrier();
  PREREAD(0);

  int cur = 0;
#pragma unroll 1
  for (int kti = 0; kti < KSTEPS; ++kti) {
    const char* ldsA = smem + cur * 65536;
    const bool stage2 = (kti + 2 < KSTEPS);

    // issue X reg-loads for tile kti+2 (latency hidden under this tile's MFMA)
    float4 x0, x1, x2, x3;
    if (stage2) {
      const float* xs = Xr + (kti + 2) * 32;
      x0 = *(const float4*)(xs + 0);
      x1 = *(const float4*)(xs + 4);
      x2 = *(const float4*)(xs + 8);
      x3 = *(const float4*)(xs + 12);
    }

    // mi-loop: pair0 pre-read at last window; rolling one-ahead for 1..7
    frag8 ah = a0h, al = a0l, nah, nal;
#pragma unroll
    for (int mi = 0; mi < 8; ++mi) {
      if (mi < 7) {
        const char* rowp = ldsA + (arow_base + (mi + 1) * 16) * 128;
        nah.v = *(const f16x8*)(rowp + offAh);
        nal.v = *(const f16x8*)(rowp + offAl);
      }
      __builtin_amdgcn_s_setprio(1);
#pragma unroll
      for (int ni = 0; ni < 4; ++ni) {
        acc[mi][ni] = __builtin_amdgcn_mfma_f32_16x16x32_f16(
            ah.v, bh[ni].v, acc[mi][ni], 0, 0, 0);
        acc[mi][ni] = __builtin_amdgcn_mfma_f32_16x16x32_f16(
            ah.v, bl[ni].v, acc[mi][ni], 0, 0, 0);
        acc[mi][ni] = __builtin_amdgcn_mfma_f32_16x16x32_f16(
            al.v, bh[ni].v, acc[mi][ni], 0, 0, 0);
      }
      __builtin_amdgcn_s_setprio(0);
      ah = nah;
      al = nal;
    }

    if (kti == KSTEPS - 1) break;
    __builtin_amdgcn_sched_barrier(0);
    __builtin_amdgcn_s_barrier();  // #1: all waves done reading smem[cur]
    if (stage2) {
      GLB(kti + 2, cur);  // B(kti+2) in flight across the barriers
      // drain B(kti+1) + X regs (8 oldest), keep B(kti+2) (4 newest) in flight
      asm volatile("s_waitcnt vmcnt(4)" ::: "memory");
    } else {
      asm volatile("s_waitcnt vmcnt(0)" ::: "memory");  // tail drain
    }
    __builtin_amdgcn_s_barrier();  // #mid: B(kti+1) image visible to all waves
    PREREAD(cur ^ 1);              // tile kti+1 frags, overlapping SPLITWR
    if (stage2) {
      SPLITWR(cur, x0, x1, x2, x3);  // A(kti+2) image into buf cur
    }
    asm volatile("s_waitcnt lgkmcnt(0)" ::: "memory");
    __builtin_amdgcn_s_barrier();  // #2: A(kti+2) written; pre-reads done
    cur ^= 1;
  }

  // ---- fused epilogue: relu(acc+b1) @ W2 chunk, 16-lane reduce ----
  __syncthreads();
  float* red = (float*)smem;  // [4][256][8] f32 = 32KB

  float bvals[4];
  float w2r[4][NE];
#pragma unroll
  for (int ni = 0; ni < 4; ++ni) {
    int c = nb * 256 + wn * 64 + ni * 16 + lane15;
    bvals[ni] = b1[c];
    const float* src = W2 + (size_t)c * NE;
#pragma unroll
    for (int e = 0; e < NE; ++e) w2r[ni][e] = src[e];
  }

#pragma unroll
  for (int mi = 0; mi < 8; ++mi) {
    float plr[4][NE];
#pragma unroll
    for (int j = 0; j < 4; ++j)
#pragma unroll
      for (int e = 0; e < NE; ++e) plr[j][e] = 0.f;
#pragma unroll
    for (int ni = 0; ni < 4; ++ni) {
#pragma unroll
      for (int j = 0; j < 4; ++j) {
        float h = acc[mi][ni][j] + bvals[ni];
        h = fmaxf(h, 0.f);
#pragma unroll
        for (int e = 0; e < NE; ++e) plr[j][e] = fmaf(h, w2r[ni][e], plr[j][e]);
      }
    }
#pragma unroll
    for (int m = 1; m < 16; m <<= 1)
#pragma unroll
      for (int j = 0; j < 4; ++j)
#pragma unroll
        for (int e = 0; e < NE; ++e)
          plr[j][e] += __shfl_xor(plr[j][e], m, 64);
    if (lane15 == 0) {
#pragma unroll
      for (int j = 0; j < 4; ++j) {
        int rr = wm * 128 + mi * 16 + lgrp * 4 + j;
#pragma unroll
        for (int e = 0; e < NE; ++e)
          red[(size_t)wn * 2048 + rr * NE + e] = plr[j][e];
      }
    }
  }
  __syncthreads();
  for (int i = t; i < 256 * NE; i += 512) {
    int r = i >> 3, e = i & 7;
    int row = rb * 256 + r;
    float s = red[i] + red[2048 + i] + red[4096 + i] + red[6144 + i];
    pl[((size_t)nb * NROWS + row) * NE + e] = s;
  }
}

// ---- finalize: sum partials + b2, softmax, top-2 ----------------------------
__global__ __launch_bounds__(256) void router_finalize(
    const float* __restrict__ pl, const float* __restrict__ b2,
    float* __restrict__ out) {
  int row = blockIdx.x * 256 + threadIdx.x;
  if (row >= NROWS) return;
  float l[NE];
#pragma unroll
  for (int e = 0; e < NE; ++e) l[e] = b2[e];
  for (int nb = 0; nb < 4; ++nb) {
    const float* src = pl + ((size_t)nb * NROWS + row) * NE;
#pragma unroll
    for (int e = 0; e < NE; ++e) l[e] += src[e];
  }
#pragma unroll
  for (int e = 0; e < NE; ++e) out[(size_t)row * NE + e] = l[e];

  float m = l[0];
#pragma unroll
  for (int e = 1; e < NE; ++e) m = fmaxf(m, l[e]);
  float p[NE], s = 0.f;
#pragma unroll
  for (int e = 0; e < NE; ++e) {
    p[e] = expf(l[e] - m);
    s += p[e];
  }
  float inv = 1.f / s;

  float v0 = -1.f, v1 = -1.f;
  int i0 = 0, i1 = 0;
#pragma unroll
  for (int e = 0; e < NE; ++e) {
    float pe = p[e];
    if (pe > v0) {
      v1 = v0; i1 = i0;
      v0 = pe; i0 = e;
    } else if (pe > v1) {
      v1 = pe; i1 = e;
    }
  }
  size_t wbase = (size_t)NROWS * NE + (size_t)row * 2;
  out[wbase] = v0 * inv;
  out[wbase + 1] = v1 * inv;
  size_t ibase = (size_t)NROWS * NE + (size_t)NROWS * 2 + (size_t)row * 2;
  out[ibase] = (float)i0;
  out[ibase + 1] = (float)i1;
}

extern "C" void kernel_launch(void* const* d_in, const int* in_sizes, int n_in,
                              void* d_out, int out_size, void* d_ws,
                              size_t ws_size, hipStream_t stream) {
  const float* X = (const float*)d_in[0];
  const float* W1 = (const float*)d_in[1];
  const float* b1 = (const float*)d_in[2];
  const float* W2 = (const float*)d_in[3];
  const float* b2 = (const float*)d_in[4];
  float* out = (float*)d_out;

  // ws: pl 2MB (at 0) | W1s 8MB (at +4MB)
  float* pl = (float*)d_ws;
  f16* W1s = (f16*)((char*)d_ws + (size_t)4 * 1024 * 1024);

  // allow 128 KiB dynamic LDS (non-stream runtime call; capture-safe)
  (void)hipFuncSetAttribute((const void*)router_mfma,
                            hipFuncAttributeMaxDynamicSharedMemorySize, 131072);

  hipLaunchKernelGGL(prep_w1, dim3(256), dim3(256), 0, stream, W1, W1s);
  hipLaunchKernelGGL(router_mfma, dim3(256), dim3(512), 131072, stream, X, W1s,
                     b1, W2, pl);
  hipLaunchKernelGGL(router_finalize, dim3(NROWS / 256), dim3(256), 0, stream,
                     pl, b2, out);
}